// Round 4
// baseline (437.973 us; speedup 1.0000x reference)
//
#include <hip/hip_runtime.h>
#include <hip/hip_cooperative_groups.h>

namespace cg = cooperative_groups;

#define BATCH 32
#define NROI  2000
#define NGT   100
#define NLBL  21
#define NPOS  64
#define GRID  1024
#define TPB   256

// native vector type for nontemporal stores (clang builtin rejects HIP float4)
typedef float nfloat4 __attribute__((ext_vector_type(4)));

__device__ __forceinline__ void nt_store(const float4& v, float4* p) {
  nfloat4 nv = {v.x, v.y, v.z, v.w};
  __builtin_nontemporal_store(nv, (nfloat4*)p);
}

// ---------------------------------------------------------------------------
// Single cooperative kernel, 3 phases separated by grid.sync():
//  A: IoU max/argmax per (b,roi)  -> composite rank key + argmax   [256 blocks]
//  B: per-batch radix-select of the 64th-largest key -> egt/lab    [32 blocks]
//  C: grid-stride coalesced nontemporal write of both outputs      [all blocks]
// Selection math is bit-exact vs numpy (_rn intrinsics, no FMA contraction;
// key = iou_bits<<16 | (0xFFFF-roi) gives stable-descending-argsort ties).
// NO early returns before the last grid.sync() — guards instead.
// ---------------------------------------------------------------------------
__global__ __launch_bounds__(TPB, 4) void roidelta_fused(
    const float4* __restrict__ roi, const float4* __restrict__ gt,
    const int* __restrict__ gtlab,
    unsigned long long* __restrict__ keys, int* __restrict__ maxidx,
    float4* __restrict__ egt, int* __restrict__ lab,
    float4* __restrict__ out) {
  cg::grid_group grid = cg::this_grid();
  const int t = threadIdx.x;
  const int bid = blockIdx.x;

  __shared__ float4 sgt[NGT];
  __shared__ float sga[NGT];
  __shared__ int hist[256];
  __shared__ int wtot[4];
  __shared__ int sbin, sneed;

  // ---------------- Phase A: IoU max/argmax (blocks 0..255: 8 chunks x 32 b)
  if (bid < 8 * BATCH) {
    const int b = bid >> 3;
    const int r = (bid & 7) * TPB + t;
    if (t < NGT) {
      float4 g = gt[b * NGT + t];
      sgt[t] = g;
      sga[t] = __fmul_rn(__fsub_rn(g.z, g.x), __fsub_rn(g.w, g.y));
    }
    __syncthreads();
    if (r < NROI) {
      // box layout [y1,x1,y2,x2]: .x=y1 .y=x1 .z=y2 .w=x2
      float4 rb = roi[b * NROI + r];
      float bb_area = __fmul_rn(__fsub_rn(rb.z, rb.x), __fsub_rn(rb.w, rb.y));
      float best = -1.0f;
      int bi = 0;
#pragma unroll 4
      for (int m = 0; m < NGT; ++m) {
        float4 g = sgt[m];
        float xt = fmaxf(rb.y, g.y);
        float yt = fmaxf(rb.x, g.x);
        float xb = fminf(rb.w, g.w);
        float yb = fminf(rb.z, g.z);
        float iw = fmaxf(__fsub_rn(xb, xt), 0.0f);
        float ih = fmaxf(__fsub_rn(yb, yt), 0.0f);
        float inter = __fmul_rn(iw, ih);
        float uni = __fsub_rn(__fadd_rn(bb_area, sga[m]), inter);  // np order
        float iou = __fdiv_rn(inter, uni);
        if (iou > best) { best = iou; bi = m; }
      }
      unsigned int fb = __float_as_uint(best);  // iou >= 0: bits order-monotone
      keys[b * NROI + r] =
          ((unsigned long long)fb << 16) | (unsigned long long)(0xFFFFu - (unsigned)r);
      maxidx[b * NROI + r] = bi;
    }
  }
  __threadfence();
  grid.sync();

  // ---------------- Phase B: radix-select 64th-largest key (blocks 0..31)
  if (bid < BATCH) {
    const int b = bid;
    unsigned long long k[8];
#pragma unroll
    for (int j = 0; j < 8; ++j) {
      int i = t + j * 256;
      k[j] = (i < NROI) ? keys[b * NROI + i] : 0ull;  // dummy 0: never selected
    }
    unsigned long long prefix = 0;
    int need = NPOS;  // 1-indexed rank of the boundary element
    const int lane = t & 63;
#pragma unroll
    for (int p = 0; p < 6; ++p) {
      const int shift = 40 - 8 * p;
      hist[t] = 0;
      __syncthreads();                               // zeros visible
      const unsigned long long hmask = ~((1ull << (shift + 8)) - 1);
#pragma unroll
      for (int j = 0; j < 8; ++j) {
        if ((k[j] & hmask) == prefix)
          atomicAdd(&hist[(int)((k[j] >> shift) & 255)], 1);
      }
      __syncthreads();                               // histogram complete
      int v = hist[t];
      int S = v;                                     // suffix sum, wave's 64 bins
#pragma unroll
      for (int off = 1; off < 64; off <<= 1) {
        int u = __shfl_down(S, off, 64);
        if (lane + off < 64) S += u;
      }
      if (lane == 0) wtot[t >> 6] = S;
      __syncthreads();                               // wtot visible
      int w = t >> 6;
#pragma unroll
      for (int w2 = 1; w2 < 4; ++w2)
        if (w2 > w) S += wtot[w2];
      // unique crossing: S[t] >= need > S[t+1]  (S nonincreasing)
      if (S >= need && (S - v) < need) { sbin = t; sneed = need - (S - v); }
      __syncthreads();                               // sbin/sneed visible
      prefix |= ((unsigned long long)sbin) << shift;
      need = sneed;
    }
    const unsigned long long k64 = prefix;  // exact key of the 64th largest
#pragma unroll
    for (int j = 0; j < 8; ++j) {
      int i = t + j * 256;
      if (i < NROI) {
        int ridx = b * NROI + i;
        float4 g = make_float4(0.f, 0.f, 0.f, 0.f);
        int lb = 0;
        if (k[j] >= k64) {  // positive roi
          int mi = maxidx[ridx];
          g = gt[b * NGT + mi];
          lb = gtlab[b * NGT + mi];
        }
        egt[ridx] = g;   // expanded_gt_boxes (zeros for negatives)
        lab[ridx] = lb;
      }
    }
  }
  __threadfence();
  grid.sync();

  // ---------------- Phase C: write outputs, grid-stride, nontemporal
  const int ND4 = BATCH * NROI * NLBL;        // 1,344,000 delta float4 rows
  const int NL4 = ND4 / 4;                    //   336,000 label float4s
  const int total4 = ND4 + NL4;
  for (int i = bid * TPB + t; i < total4; i += GRID * TPB) {
    if (i < ND4) {
      int b = i / (NROI * NLBL);
      int rem = i - b * (NROI * NLBL);
      int r = rem / NLBL;
      int cls = rem - r * NLBL;
      int ridx = b * NROI + r;
      float4 v = make_float4(0.f, 0.f, 0.f, 0.f);
      if (cls == lab[ridx]) {
        float4 g = egt[ridx];
        float4 rb = roi[ridx];
        float bw = rb.w - rb.y, bh = rb.z - rb.x;
        float bcx = rb.y + 0.5f * bw, bcy = rb.x + 0.5f * bh;
        float gw = g.w - g.y, gh = g.z - g.x;
        float gcx = g.y + 0.5f * gw, gcy = g.x + 0.5f * gh;
        if (bw == 0.f) bw = 1e-3f;
        if (bh == 0.f) bh = 1e-3f;
        float dx  = (gw == 0.f) ? 0.f : (gcx - bcx) / bw;
        float dy  = (gh == 0.f) ? 0.f : (gcy - bcy) / bh;
        float dwv = (gw == 0.f) ? 0.f : logf(gw / bw);
        float dhv = (gh == 0.f) ? 0.f : logf(gh / bh);
        v = make_float4(dy, dx, dhv, dwv);  // [dy, dx, dh, dw]
      }
      nt_store(v, &out[i]);
    } else {
      int i2 = i - ND4;
      int e = i2 * 4;
      float v[4];
#pragma unroll
      for (int kk = 0; kk < 4; ++kk) {
        int ei = e + kk;
        int b = ei / (NROI * NLBL);
        int rem = ei - b * (NROI * NLBL);
        int r = rem / NLBL;
        int cls = rem - r * NLBL;
        v[kk] = (cls == lab[b * NROI + r]) ? 1.0f : 0.0f;
      }
      float4 vv = make_float4(v[0], v[1], v[2], v[3]);
      nt_store(vv, &out[i]);
    }
  }
}

extern "C" void kernel_launch(void* const* d_in, const int* in_sizes, int n_in,
                              void* d_out, int out_size, void* d_ws, size_t ws_size,
                              hipStream_t stream) {
  const float* roi = (const float*)d_in[0];  // (32,2000,4) fp32
  const float* gt  = (const float*)d_in[1];  // (32,100,4)  fp32
  const int* gtlab = (const int*)d_in[2];    // (32,100)    int32

  // workspace layout (bytes):
  //   [0,512000)           keys    u64[64000]
  //   [512000,768000)      maxidx  i32[64000]
  //   [768000,1792000)     egt     float4[64000]  (16B aligned)
  //   [1792000,2048000)    lab     i32[64000]
  char* ws = (char*)d_ws;
  unsigned long long* keys = (unsigned long long*)ws;
  int*    maxidx = (int*)(ws + 512000);
  float4* egt    = (float4*)(ws + 768000);
  int*    lab    = (int*)(ws + 1792000);

  const float4* roi4 = (const float4*)roi;
  const float4* gt4  = (const float4*)gt;
  float4* out4 = (float4*)d_out;

  void* args[] = {(void*)&roi4, (void*)&gt4, (void*)&gtlab,
                  (void*)&keys, (void*)&maxidx, (void*)&egt, (void*)&lab,
                  (void*)&out4};
  hipLaunchCooperativeKernel((const void*)roidelta_fused, dim3(GRID), dim3(TPB),
                             args, 0, stream);
}

// Round 5
// 96.568 us; speedup vs baseline: 4.5354x; 4.5354x over previous
//
#include <hip/hip_runtime.h>

#define BATCH 32
#define NROI  2000
#define NGT   100
#define NLBL  21
#define NPOS  64

// native vector type for nontemporal stores (clang builtin rejects HIP float4)
typedef float nfloat4 __attribute__((ext_vector_type(4)));

__device__ __forceinline__ void nt_store(const float4& v, float4* p) {
  nfloat4 nv = {v.x, v.y, v.z, v.w};
  __builtin_nontemporal_store(nv, (nfloat4*)p);
}

// ---------------------------------------------------------------------------
// K1+K2 fused: grid (8, 32), 256 threads.
// Phase A (all blocks): per (b,roi) IoU max/argmax over 100 gts, composite key
//   key = iou_bits<<16 | (0xFFFF-roi)  (stable descending-argsort semantics;
//   _rn intrinsics forbid FMA contraction -> bit-match numpy; a selection flip
//   is the only way to blow the 0.02 threshold).
// Then each block release-stores done[b*8+chunk]=1 (agent scope).
// Phase B (chunk-0 block of each batch): acquire-spin on the batch's 8 flags,
// then radix-select the 64th-largest key (6 MSB-first 8-bit passes) and write
// egt/lab. Deadlock-free: producers never wait; 32 spinners on a 256-CU chip.
// Reset-safe: ws poison (0xAAAAAAAA != 1) resets flags and keys together.
// NO cooperative grid.sync — measured 370 us of pure stall in R4.
// ---------------------------------------------------------------------------
__global__ __launch_bounds__(256) void iou_select_kernel(
    const float4* __restrict__ roi, const float4* __restrict__ gt,
    const int* __restrict__ gtlab,
    unsigned long long* __restrict__ keys, int* __restrict__ maxidx,
    float4* __restrict__ egt, int* __restrict__ lab,
    unsigned int* __restrict__ done) {
  const int chunk = blockIdx.x;   // 0..7
  const int b = blockIdx.y;       // 0..31
  const int t = threadIdx.x;
  __shared__ float4 sgt[NGT];
  __shared__ float sga[NGT];

  // ---------------- Phase A: IoU max/argmax for roi r = chunk*256 + t
  if (t < NGT) {
    float4 g = gt[b * NGT + t];
    sgt[t] = g;
    sga[t] = __fmul_rn(__fsub_rn(g.z, g.x), __fsub_rn(g.w, g.y));
  }
  __syncthreads();
  const int r = chunk * 256 + t;
  if (r < NROI) {
    // box layout [y1,x1,y2,x2]: .x=y1 .y=x1 .z=y2 .w=x2
    float4 rb = roi[b * NROI + r];
    float bb_area = __fmul_rn(__fsub_rn(rb.z, rb.x), __fsub_rn(rb.w, rb.y));
    float best = -1.0f;
    int bi = 0;
#pragma unroll 4
    for (int m = 0; m < NGT; ++m) {
      float4 g = sgt[m];
      float xt = fmaxf(rb.y, g.y);
      float yt = fmaxf(rb.x, g.x);
      float xb = fminf(rb.w, g.w);
      float yb = fminf(rb.z, g.z);
      float iw = fmaxf(__fsub_rn(xb, xt), 0.0f);
      float ih = fmaxf(__fsub_rn(yb, yt), 0.0f);
      float inter = __fmul_rn(iw, ih);
      float uni = __fsub_rn(__fadd_rn(bb_area, sga[m]), inter);  // np eval order
      float iou = __fdiv_rn(inter, uni);
      if (iou > best) { best = iou; bi = m; }
    }
    unsigned int fb = __float_as_uint(best);  // iou >= 0: bits order-monotone
    keys[b * NROI + r] =
        ((unsigned long long)fb << 16) | (unsigned long long)(0xFFFFu - (unsigned)r);
    maxidx[b * NROI + r] = bi;
  }
  __syncthreads();  // barrier drains vmcnt: block's key/maxidx stores complete
  if (t == 0)
    __hip_atomic_store(&done[b * 8 + chunk], 1u, __ATOMIC_RELEASE,
                       __HIP_MEMORY_SCOPE_AGENT);
  if (chunk != 0) return;

  // ---------------- Phase B (chunk-0 blocks only): wait for siblings
  if (t < 8) {
    while (__hip_atomic_load(&done[b * 8 + t], __ATOMIC_ACQUIRE,
                             __HIP_MEMORY_SCOPE_AGENT) != 1u)
      __builtin_amdgcn_s_sleep(2);
  }
  __syncthreads();

  unsigned long long k[8];
#pragma unroll
  for (int j = 0; j < 8; ++j) {
    int i = t + j * 256;
    k[j] = (i < NROI) ? keys[b * NROI + i] : 0ull;  // dummy 0: never selected
  }
  __shared__ int hist[256];
  __shared__ int wtot[4];
  __shared__ int sbin, sneed;
  unsigned long long prefix = 0;
  int need = NPOS;  // 1-indexed rank of the boundary element
  const int lane = t & 63;
#pragma unroll
  for (int p = 0; p < 6; ++p) {
    const int shift = 40 - 8 * p;
    hist[t] = 0;
    __syncthreads();                               // zeros visible
    const unsigned long long hmask = ~((1ull << (shift + 8)) - 1);
#pragma unroll
    for (int j = 0; j < 8; ++j) {
      if ((k[j] & hmask) == prefix)
        atomicAdd(&hist[(int)((k[j] >> shift) & 255)], 1);
    }
    __syncthreads();                               // histogram complete
    int v = hist[t];
    int S = v;                                     // suffix sum, wave's 64 bins
#pragma unroll
    for (int off = 1; off < 64; off <<= 1) {
      int u = __shfl_down(S, off, 64);
      if (lane + off < 64) S += u;
    }
    if (lane == 0) wtot[t >> 6] = S;
    __syncthreads();                               // wtot visible
    int w = t >> 6;
#pragma unroll
    for (int w2 = 1; w2 < 4; ++w2)
      if (w2 > w) S += wtot[w2];
    // unique crossing: S[t] >= need > S[t+1]  (S nonincreasing)
    if (S >= need && (S - v) < need) { sbin = t; sneed = need - (S - v); }
    __syncthreads();                               // sbin/sneed visible
    prefix |= ((unsigned long long)sbin) << shift;
    need = sneed;
  }
  const unsigned long long k64 = prefix;  // exact key of the 64th largest
#pragma unroll
  for (int j = 0; j < 8; ++j) {
    int i = t + j * 256;
    if (i < NROI) {
      int ridx = b * NROI + i;
      float4 g = make_float4(0.f, 0.f, 0.f, 0.f);
      int lb = 0;
      if (k[j] >= k64) {  // positive roi
        int mi = maxidx[ridx];
        g = gt[b * NGT + mi];
        lb = gtlab[b * NGT + mi];
      }
      egt[ridx] = g;   // expanded_gt_boxes (zeros for negatives)
      lab[ridx] = lb;
    }
  }
}

// ---------------------------------------------------------------------------
// K3: coalesced nontemporal float4 writer of both outputs; delta computed in
// the single (cls == label) thread per roi. Negative rois: egt = 0 -> gw = gh
// = 0 -> all deltas 0 (same guard as reference).
//   out[0 .. 1343999]       : delta rows, one float4 per (b, roi, cls)
//   out[1344000 .. 1679999] : labels, 4 consecutive fp32 per float4
// ---------------------------------------------------------------------------
__global__ __launch_bounds__(256) void write_out_kernel(
    const float4* __restrict__ roi, const float4* __restrict__ egt,
    const int* __restrict__ lab, float4* __restrict__ out) {
  const int ND4 = BATCH * NROI * NLBL;        // 1,344,000 delta float4 rows
  const int NL4 = (BATCH * NROI * NLBL) / 4;  //   336,000 label float4s
  int i = blockIdx.x * 256 + threadIdx.x;
  if (i < ND4) {
    int b = i / (NROI * NLBL);
    int rem = i - b * (NROI * NLBL);
    int r = rem / NLBL;
    int cls = rem - r * NLBL;
    int ridx = b * NROI + r;
    float4 v = make_float4(0.f, 0.f, 0.f, 0.f);
    if (cls == lab[ridx]) {
      float4 g = egt[ridx];
      float4 rb = roi[ridx];
      float bw = rb.w - rb.y, bh = rb.z - rb.x;
      float bcx = rb.y + 0.5f * bw, bcy = rb.x + 0.5f * bh;
      float gw = g.w - g.y, gh = g.z - g.x;
      float gcx = g.y + 0.5f * gw, gcy = g.x + 0.5f * gh;
      if (bw == 0.f) bw = 1e-3f;
      if (bh == 0.f) bh = 1e-3f;
      float dx  = (gw == 0.f) ? 0.f : (gcx - bcx) / bw;
      float dy  = (gh == 0.f) ? 0.f : (gcy - bcy) / bh;
      float dwv = (gw == 0.f) ? 0.f : logf(gw / bw);
      float dhv = (gh == 0.f) ? 0.f : logf(gh / bh);
      v = make_float4(dy, dx, dhv, dwv);  // [dy, dx, dh, dw]
    }
    nt_store(v, &out[i]);
  } else if (i < ND4 + NL4) {
    int i2 = i - ND4;
    int e = i2 * 4;
    float v[4];
#pragma unroll
    for (int kk = 0; kk < 4; ++kk) {
      int ei = e + kk;
      int b = ei / (NROI * NLBL);
      int rem = ei - b * (NROI * NLBL);
      int r = rem / NLBL;
      int cls = rem - r * NLBL;
      v[kk] = (cls == lab[b * NROI + r]) ? 1.0f : 0.0f;
    }
    float4 vv = make_float4(v[0], v[1], v[2], v[3]);
    nt_store(vv, &out[i]);
  }
}

extern "C" void kernel_launch(void* const* d_in, const int* in_sizes, int n_in,
                              void* d_out, int out_size, void* d_ws, size_t ws_size,
                              hipStream_t stream) {
  const float* roi = (const float*)d_in[0];  // (32,2000,4) fp32
  const float* gt  = (const float*)d_in[1];  // (32,100,4)  fp32
  const int* gtlab = (const int*)d_in[2];    // (32,100)    int32

  // workspace layout (bytes):
  //   [0,512000)           keys    u64[64000]
  //   [512000,768000)      maxidx  i32[64000]
  //   [768000,1792000)     egt     float4[64000]  (16B aligned)
  //   [1792000,2048000)    lab     i32[64000]
  //   [2048000,2049024)    done    u32[256]
  char* ws = (char*)d_ws;
  unsigned long long* keys = (unsigned long long*)ws;
  int*    maxidx = (int*)(ws + 512000);
  float4* egt    = (float4*)(ws + 768000);
  int*    lab    = (int*)(ws + 1792000);
  unsigned int* done = (unsigned int*)(ws + 2048000);

  iou_select_kernel<<<dim3(8, BATCH), 256, 0, stream>>>(
      (const float4*)roi, (const float4*)gt, gtlab, keys, maxidx, egt, lab, done);
  const int total4 = BATCH * NROI * NLBL + (BATCH * NROI * NLBL) / 4;  // 1,680,000
  write_out_kernel<<<dim3((total4 + 255) / 256), 256, 0, stream>>>(
      (const float4*)roi, egt, lab, (float4*)d_out);
}

// Round 6
// 88.069 us; speedup vs baseline: 4.9731x; 1.0965x over previous
//
#include <hip/hip_runtime.h>

#define BATCH 32
#define NROI  2000
#define NGT   100
#define NLBL  21
#define NPOS  64

// native vector type for nontemporal stores (clang builtin rejects HIP float4)
typedef float nfloat4 __attribute__((ext_vector_type(4)));

__device__ __forceinline__ void nt_store(const float4& v, float4* p) {
  nfloat4 nv = {v.x, v.y, v.z, v.w};
  __builtin_nontemporal_store(nv, (nfloat4*)p);
}

// ---------------------------------------------------------------------------
// R6 = revert to the R3 3-kernel pipeline (88.3 us, absmax 0.0).
// Journal: R4 cooperative grid.sync = ~175 us/sync at grid 1024 (kernel 370 us,
// 95% idle). R5 agent-scope release/acquire spin fusion = +8 us net vs a plain
// extra dispatch (cross-XCD L2 writeback/invalidate per flag op). On MI355X a
// ~3 us graph dispatch gap beats every inter-block sync primitive at this
// scale. Batch-per-block fusion (32x1024) loses 8x IoU parallelism -> ~23 us
// by issue-port arithmetic. Structure below is the floor: K1 full-chip IoU,
// K2 tiny select, K3 write-BW-bound output expansion.
// ---------------------------------------------------------------------------

// K1: per (b, roi) max/argmax IoU over 100 gt boxes (strict > = first-max,
// matching jnp.argmax). Composite rank key:
//   key = (float_bits(max_iou) << 16) | (0xFFFF - roi)
// iou >= 0 so float bits are order-monotonic; lower roi wins ties (stable
// descending argsort). _rn intrinsics forbid FMA contraction so the rounded
// quotients bit-match the numpy reference (selection flips are the only
// way to blow the 0.02 absmax threshold).
__global__ __launch_bounds__(256) void iou_max_kernel(
    const float4* __restrict__ roi, const float4* __restrict__ gt,
    unsigned long long* __restrict__ keys, int* __restrict__ maxidx) {
  __shared__ float4 sgt[NGT];
  __shared__ float sga[NGT];
  const int b = blockIdx.y;
  const int r = blockIdx.x * 256 + threadIdx.x;
  if (threadIdx.x < NGT) {
    float4 g = gt[b * NGT + threadIdx.x];
    sgt[threadIdx.x] = g;
    sga[threadIdx.x] = __fmul_rn(__fsub_rn(g.z, g.x), __fsub_rn(g.w, g.y));
  }
  __syncthreads();
  if (r >= NROI) return;
  // box layout [y1,x1,y2,x2]: .x=y1 .y=x1 .z=y2 .w=x2
  float4 rb = roi[b * NROI + r];
  float bb_area = __fmul_rn(__fsub_rn(rb.z, rb.x), __fsub_rn(rb.w, rb.y));
  float best = -1.0f;
  int bi = 0;
#pragma unroll 4
  for (int m = 0; m < NGT; ++m) {
    float4 g = sgt[m];
    float xt = fmaxf(rb.y, g.y);
    float yt = fmaxf(rb.x, g.x);
    float xb = fminf(rb.w, g.w);
    float yb = fminf(rb.z, g.z);
    float iw = fmaxf(__fsub_rn(xb, xt), 0.0f);
    float ih = fmaxf(__fsub_rn(yb, yt), 0.0f);
    float inter = __fmul_rn(iw, ih);
    float uni = __fsub_rn(__fadd_rn(bb_area, sga[m]), inter);  // left-to-right like np
    float iou = __fdiv_rn(inter, uni);
    if (iou > best) { best = iou; bi = m; }
  }
  unsigned int fb = __float_as_uint(best);
  keys[b * NROI + r] =
      ((unsigned long long)fb << 16) | (unsigned long long)(0xFFFFu - (unsigned)r);
  maxidx[b * NROI + r] = bi;
}

// K2: one block per batch. Radix-select the 64th-largest key (MSB-first,
// 8-bit digits, 6 passes; keys < 2^46). Keys live in registers (8/thread).
// Each pass: LDS histogram -> block-wide suffix scan -> descend into the bin
// holding the need-th largest. Keys are distinct so pos <=> key >= K64.
__global__ __launch_bounds__(256) void select_kernel(
    const unsigned long long* __restrict__ keys, const int* __restrict__ maxidx,
    const float4* __restrict__ gt, const int* __restrict__ gtlab,
    float4* __restrict__ egt, int* __restrict__ lab) {
  const int b = blockIdx.x;
  const int t = threadIdx.x;
  unsigned long long k[8];
#pragma unroll
  for (int j = 0; j < 8; ++j) {
    int i = t + j * 256;
    k[j] = (i < NROI) ? keys[b * NROI + i] : 0ull;  // dummy 0: never selected
  }
  __shared__ int hist[256];
  __shared__ int wtot[4];
  __shared__ int sbin, sneed;
  unsigned long long prefix = 0;
  int need = NPOS;  // 1-indexed rank of the boundary element
  const int lane = t & 63;
#pragma unroll
  for (int p = 0; p < 6; ++p) {
    const int shift = 40 - 8 * p;
    hist[t] = 0;
    __syncthreads();                               // zeros visible
    const unsigned long long hmask = ~((1ull << (shift + 8)) - 1);
#pragma unroll
    for (int j = 0; j < 8; ++j) {
      if ((k[j] & hmask) == prefix)
        atomicAdd(&hist[(int)((k[j] >> shift) & 255)], 1);
    }
    __syncthreads();                               // histogram complete
    int v = hist[t];
    int S = v;                                     // suffix sum within wave's 64 bins
#pragma unroll
    for (int off = 1; off < 64; off <<= 1) {
      int u = __shfl_down(S, off, 64);
      if (lane + off < 64) S += u;
    }
    if (lane == 0) wtot[t >> 6] = S;               // wave total
    __syncthreads();                               // wtot visible
    int w = t >> 6;
#pragma unroll
    for (int w2 = 1; w2 < 4; ++w2)
      if (w2 > w) S += wtot[w2];
    // unique crossing: S[t] >= need > S[t+1]  (S nonincreasing, S[0] >= need)
    if (S >= need && (S - v) < need) { sbin = t; sneed = need - (S - v); }
    __syncthreads();                               // sbin/sneed visible
    prefix |= ((unsigned long long)sbin) << shift;
    need = sneed;
  }
  const unsigned long long k64 = prefix;  // exact key of the 64th largest
#pragma unroll
  for (int j = 0; j < 8; ++j) {
    int i = t + j * 256;
    if (i < NROI) {
      int ridx = b * NROI + i;
      float4 g = make_float4(0.f, 0.f, 0.f, 0.f);
      int lb = 0;
      if (k[j] >= k64) {  // positive roi
        int mi = maxidx[ridx];
        g = gt[b * NGT + mi];
        lb = gtlab[b * NGT + mi];
      }
      egt[ridx] = g;   // expanded_gt_boxes semantics (zeros for negatives)
      lab[ridx] = lb;
    }
  }
}

// K3: coalesced nontemporal float4 writer of both outputs; delta computed in
// the single (cls == label) thread per roi. Negative rois: egt = 0 -> gw = gh
// = 0 -> all deltas 0 (same guard as reference).
//   out[0 .. 1343999]       : delta rows, one float4 per (b, roi, cls)
//   out[1344000 .. 1679999] : labels, 4 consecutive fp32 per float4
__global__ __launch_bounds__(256) void write_out_kernel(
    const float4* __restrict__ roi, const float4* __restrict__ egt,
    const int* __restrict__ lab, float4* __restrict__ out) {
  const int ND4 = BATCH * NROI * NLBL;        // 1,344,000 delta float4 rows
  const int NL4 = (BATCH * NROI * NLBL) / 4;  //   336,000 label float4s
  int i = blockIdx.x * 256 + threadIdx.x;
  if (i < ND4) {
    int b = i / (NROI * NLBL);
    int rem = i - b * (NROI * NLBL);
    int r = rem / NLBL;
    int cls = rem - r * NLBL;
    int ridx = b * NROI + r;
    float4 v = make_float4(0.f, 0.f, 0.f, 0.f);
    if (cls == lab[ridx]) {
      float4 g = egt[ridx];
      float4 rb = roi[ridx];
      float bw = rb.w - rb.y, bh = rb.z - rb.x;
      float bcx = rb.y + 0.5f * bw, bcy = rb.x + 0.5f * bh;
      float gw = g.w - g.y, gh = g.z - g.x;
      float gcx = g.y + 0.5f * gw, gcy = g.x + 0.5f * gh;
      if (bw == 0.f) bw = 1e-3f;
      if (bh == 0.f) bh = 1e-3f;
      float dx  = (gw == 0.f) ? 0.f : (gcx - bcx) / bw;
      float dy  = (gh == 0.f) ? 0.f : (gcy - bcy) / bh;
      float dwv = (gw == 0.f) ? 0.f : logf(gw / bw);
      float dhv = (gh == 0.f) ? 0.f : logf(gh / bh);
      v = make_float4(dy, dx, dhv, dwv);  // [dy, dx, dh, dw]
    }
    nt_store(v, &out[i]);
  } else if (i < ND4 + NL4) {
    int i2 = i - ND4;
    int e = i2 * 4;
    float v[4];
#pragma unroll
    for (int kk = 0; kk < 4; ++kk) {
      int ei = e + kk;
      int b = ei / (NROI * NLBL);
      int rem = ei - b * (NROI * NLBL);
      int r = rem / NLBL;
      int cls = rem - r * NLBL;
      v[kk] = (cls == lab[b * NROI + r]) ? 1.0f : 0.0f;
    }
    float4 vv = make_float4(v[0], v[1], v[2], v[3]);
    nt_store(vv, &out[i]);
  }
}

extern "C" void kernel_launch(void* const* d_in, const int* in_sizes, int n_in,
                              void* d_out, int out_size, void* d_ws, size_t ws_size,
                              hipStream_t stream) {
  const float* roi = (const float*)d_in[0];  // (32,2000,4) fp32
  const float* gt  = (const float*)d_in[1];  // (32,100,4)  fp32
  const int* gtlab = (const int*)d_in[2];    // (32,100)    int32

  // workspace layout (bytes):
  //   [0,512000)           keys    u64[64000]
  //   [512000,768000)      maxidx  i32[64000]
  //   [768000,1792000)     egt     float4[64000]  (16B aligned)
  //   [1792000,2048000)    lab     i32[64000]
  char* ws = (char*)d_ws;
  unsigned long long* keys = (unsigned long long*)ws;
  int*    maxidx = (int*)(ws + 512000);
  float4* egt    = (float4*)(ws + 768000);
  int*    lab    = (int*)(ws + 1792000);

  iou_max_kernel<<<dim3(8, BATCH), 256, 0, stream>>>(
      (const float4*)roi, (const float4*)gt, keys, maxidx);
  select_kernel<<<dim3(BATCH), 256, 0, stream>>>(
      keys, maxidx, (const float4*)gt, gtlab, egt, lab);
  const int total4 = BATCH * NROI * NLBL + (BATCH * NROI * NLBL) / 4;  // 1,680,000
  write_out_kernel<<<dim3((total4 + 255) / 256), 256, 0, stream>>>(
      (const float4*)roi, egt, lab, (float4*)d_out);
}